// Round 1
// baseline (748.183 us; speedup 1.0000x reference)
//
#include <hip/hip_runtime.h>

// RGCN round 1: correctness-first, MFMA for the adjacency einsum.
//
// Decomposition:
//   deg/inv:  deg[b,n] = sum_{e,m} adjz[b,e,m,n]  (diag zeroed), inv = 1/deg
//   per layer l:
//     hs  = h @ w_self + b_self                     (fp32 tiled GEMM)
//     mmp[b,e,m,o] = inv[b,m]*(h @ w_edge + b_edge) (fp32 GEMM -> bf16, k-packed)
//     hpre[b,n,o] = hs + sum_{e,m} adjz[b,e,n,m]*mmp[b,e,m,o]   (bf16 MFMA)
//     BN over (b,o) per node n, relu
//   head: w1 -> BN -> relu -> w2
//
// inv folding: na[b,e,n,m] = inv[b,m]*adjz -> scale edge-message ROW m by inv[b,m];
// na never materialized, adj read raw with inline diag masking + f32->bf16 cvt.
//
// mmp k-packed layout [b][e][m>>3][o][m&7]: spmm B staging = contiguous LDS copy,
// B-frag = ds_read_b128 (lane l: B[k=(l>>4)*8+j][col=c*16+(l&15)]).
// MFMA C/D: row=(l>>4)*4+reg, col=l&15 (m89-verified).

typedef float  f32x4  __attribute__((ext_vector_type(4)));
typedef __bf16 bf16x8 __attribute__((ext_vector_type(8)));
typedef __bf16 bf16x4 __attribute__((ext_vector_type(4)));

#define MBATCH 32
#define ETYPES 4
#define NNODE  512
#define HIDD   128
// M = MBATCH*NNODE = 16384 rows

// ---------------- deg: column sums of adj (diag excluded) ----------------
// grid 256 = (b:32, mc:8), 64 rows per block, e-loop inside. atomicAdd into deg.
__global__ __launch_bounds__(256) void k_deg(const float* __restrict__ adj,
                                             float* __restrict__ deg) {
  int bx = blockIdx.x;
  int b = bx >> 3, mc = bx & 7;
  int t = threadIdx.x;
  int col4 = t & 127;                 // invariant under +=256 stepping
  float ps0 = 0.f, ps1 = 0.f, ps2 = 0.f, ps3 = 0.f;
  for (int e = 0; e < ETYPES; ++e) {
    const float* base = adj + ((b * ETYPES + e) * NNODE + mc * 64) * NNODE;
    for (int i = 0; i < 32; ++i) {
      int idx = t + i * 256;
      int row = idx >> 7;             // 0..63
      f32x4 v = *(const f32x4*)(base + row * NNODE + col4 * 4);
      int m = mc * 64 + row;
      int n = col4 * 4;
      if (m == n)     v.x = 0.f;
      if (m == n + 1) v.y = 0.f;
      if (m == n + 2) v.z = 0.f;
      if (m == n + 3) v.w = 0.f;
      ps0 += v.x; ps1 += v.y; ps2 += v.z; ps3 += v.w;
    }
  }
  __shared__ float cs[256][4];
  cs[t][0] = ps0; cs[t][1] = ps1; cs[t][2] = ps2; cs[t][3] = ps3;
  __syncthreads();
  if (t < 128) {
    float* dd = deg + b * NNODE + col4 * 4;
    atomicAdd(dd + 0, ps0 + cs[t + 128][0]);
    atomicAdd(dd + 1, ps1 + cs[t + 128][1]);
    atomicAdd(dd + 2, ps2 + cs[t + 128][2]);
    atomicAdd(dd + 3, ps3 + cs[t + 128][3]);
  }
}

__global__ __launch_bounds__(256) void k_inv(const float* __restrict__ deg,
                                             float* __restrict__ inv) {
  int i = blockIdx.x * 256 + threadIdx.x;   // grid 64 -> 16384
  float d = deg[i];
  inv[i] = d > 0.f ? 1.f / d : 0.f;
}

// ---------------- fp32 tiled linear: 64 rows x 64 cols per block ----------------
// EDGE=false: out[g][c0+c] = h@W + bias   (W stride 128)
// EDGE=true : mmp packed bf16 = inv[g]*(h@W + bias)  (W stride 512)
template <int K, bool EDGE>
__global__ __launch_bounds__(256) void k_lin(const float* __restrict__ h,
                                             const float* __restrict__ W,
                                             const float* __restrict__ bias,
                                             const float* __restrict__ invp,
                                             float* __restrict__ out,
                                             __bf16* __restrict__ mmp) {
  constexpr int WS = EDGE ? 512 : 128;
  __shared__ float wt[K][64];
  __shared__ float ht[64][K];
  int t = threadIdx.x;
  int g0 = blockIdx.x * 64;
  int c0 = blockIdx.y * 64;
  for (int idx = t; idx < K * 16; idx += 256) {
    int k = idx >> 4, c4 = idx & 15;
    *(f32x4*)&wt[k][c4 * 4] = *(const f32x4*)(W + k * WS + c0 + c4 * 4);
  }
  for (int idx = t; idx < 64 * (K / 4); idx += 256) {
    int r = idx / (K / 4), k4 = idx % (K / 4);
    *(f32x4*)&ht[r][k4 * 4] = *(const f32x4*)(h + (g0 + r) * K + k4 * 4);
  }
  __syncthreads();
  int rq = t >> 4, cq = t & 15;
  f32x4 acc[4] = {};
  for (int k0 = 0; k0 < K; k0 += 4) {
    f32x4 hv[4], wv[4];
#pragma unroll
    for (int i = 0; i < 4; ++i) hv[i] = *(const f32x4*)&ht[rq * 4 + i][k0];
#pragma unroll
    for (int j = 0; j < 4; ++j) wv[j] = *(const f32x4*)&wt[k0 + j][cq * 4];
#pragma unroll
    for (int kk = 0; kk < 4; ++kk) {
#pragma unroll
      for (int i = 0; i < 4; ++i) acc[i] += hv[i][kk] * wv[kk];
    }
  }
  f32x4 bias4 = *(const f32x4*)(bias + c0 + cq * 4);
  if (!EDGE) {
#pragma unroll
    for (int i = 0; i < 4; ++i) {
      int g = g0 + rq * 4 + i;
      *(f32x4*)(out + g * HIDD + c0 + cq * 4) = acc[i] + bias4;
    }
  } else {
#pragma unroll
    for (int i = 0; i < 4; ++i) {
      int g = g0 + rq * 4 + i;
      int b = g >> 9, m = g & 511;
      float iv = invp[g];
#pragma unroll
      for (int j = 0; j < 4; ++j) {
        int ce = c0 + cq * 4 + j;     // 0..511
        int o = ce >> 2, e = ce & 3;  // reshape (HID,E): c = o*E + e
        float val = (acc[i][j] + bias4[j]) * iv;
        mmp[(((b * ETYPES + e) * 64 + (m >> 3)) * HIDD + o) * 8 + (m & 7)] = (__bf16)val;
      }
    }
  }
}

// ---------------- spmm: hpre = hs + sum_e adjz(bf16) @ mmp(bf16), MFMA ----------------
// grid 256 = (b:32, ntile:8); block = 4 waves, wave w owns rows [w*16,w*16+16), cols 0..128
__global__ __launch_bounds__(256) void k_spmm(const float* __restrict__ adj,
                                              const __bf16* __restrict__ mmp,
                                              const float* __restrict__ hs,
                                              float* __restrict__ out) {
  __shared__ __bf16 Al[64][72];     // +8 pad breaks 128B row stride
  __shared__ __bf16 Bl[8192];       // k-packed chunk: [oct(8)][o(128)][j(8)]
  int t = threadIdx.x;
  int b = blockIdx.x >> 3, ntile = blockIdx.x & 7;
  int n0 = ntile * 64;
  int wave = t >> 6, lane = t & 63, l15 = lane & 15, q = lane >> 4;
  f32x4 acc[8] = {};
  for (int e = 0; e < ETYPES; ++e) {
    const float*  Abase = adj + ((b * ETYPES + e) * NNODE + n0) * NNODE;
    const __bf16* Bbase = mmp + (b * ETYPES + e) * 65536;
    for (int mc = 0; mc < 8; ++mc) {
      __syncthreads();
      // stage A tile 64n x 64m, f32 -> bf16, diag masked
#pragma unroll
      for (int i = 0; i < 4; ++i) {
        int idx = t + i * 256;
        int row = idx >> 4, seg = idx & 15;
        f32x4 v = *(const f32x4*)(Abase + row * NNODE + mc * 64 + seg * 4);
        int mg = mc * 64 + seg * 4, ng = n0 + row;
        bf16x4 bw;
#pragma unroll
        for (int j = 0; j < 4; ++j) bw[j] = (mg + j == ng) ? (__bf16)0.f : (__bf16)v[j];
        *(bf16x4*)&Al[row][seg * 4] = bw;
      }
      // stage B chunk: contiguous 16KB copy
      {
        const f32x4* Bs = (const f32x4*)(Bbase + mc * 8192);
        f32x4* Bd = (f32x4*)Bl;
#pragma unroll
        for (int i = 0; i < 4; ++i) Bd[t + i * 256] = Bs[t + i * 256];
      }
      __syncthreads();
#pragma unroll
      for (int kk = 0; kk < 2; ++kk) {
        bf16x8 af = *(const bf16x8*)&Al[wave * 16 + l15][kk * 32 + q * 8];
#pragma unroll
        for (int c = 0; c < 8; ++c) {
          bf16x8 bf = *(const bf16x8*)&Bl[(kk * 4 + q) * 1024 + (c * 16 + l15) * 8];
          acc[c] = __builtin_amdgcn_mfma_f32_16x16x32_bf16(af, bf, acc[c], 0, 0, 0);
        }
      }
    }
  }
#pragma unroll
  for (int c = 0; c < 8; ++c) {
#pragma unroll
    for (int i = 0; i < 4; ++i) {
      int n = n0 + wave * 16 + q * 4 + i;   // D row=(l>>4)*4+reg
      int o = c * 16 + l15;                 // D col=lane&15
      int idx = (b * NNODE + n) * HIDD + o;
      out[idx] = hs[idx] + acc[c][i];
    }
  }
}

// ---------------- BN stats per node n over (b, o): 4096 values ----------------
__global__ __launch_bounds__(256) void k_stats(const float* __restrict__ hp,
                                               const float* __restrict__ gg,
                                               const float* __restrict__ bb,
                                               float* __restrict__ ss) {
  int n = blockIdx.x, t = threadIdx.x;
  int o4 = t & 31, bq = t >> 5;
  float s = 0.f, sq = 0.f;
#pragma unroll
  for (int i = 0; i < 4; ++i) {
    int b = bq + i * 8;
    f32x4 v = *(const f32x4*)(hp + (b * NNODE + n) * HIDD + o4 * 4);
#pragma unroll
    for (int j = 0; j < 4; ++j) { s += v[j]; sq += v[j] * v[j]; }
  }
  __shared__ float rs[256], rq[256];
  rs[t] = s; rq[t] = sq;
  __syncthreads();
  for (int off = 128; off > 0; off >>= 1) {
    if (t < off) { rs[t] += rs[t + off]; rq[t] += rq[t + off]; }
    __syncthreads();
  }
  if (t == 0) {
    float mean = rs[0] * (1.f / 4096.f);
    float var = rq[0] * (1.f / 4096.f) - mean * mean;   // biased, torch BN1d
    float rstd = rsqrtf(var + 1e-5f);
    float sc = gg[n] * rstd;
    ss[n] = sc;
    ss[512 + n] = bb[n] - mean * sc;
  }
}

__global__ __launch_bounds__(256) void k_bnrelu(float* __restrict__ h,
                                                const float* __restrict__ ss) {
  int idx = blockIdx.x * 256 + threadIdx.x;   // f32x4 index, grid 2048
  int n = (idx >> 5) & 511;
  f32x4 v = *(f32x4*)(h + idx * 4);
  float sc = ss[n], sh = ss[512 + n];
#pragma unroll
  for (int j = 0; j < 4; ++j) {
    float x = v[j] * sc + sh;
    v[j] = x > 0.f ? x : 0.f;
  }
  *(f32x4*)(h + idx * 4) = v;
}

extern "C" void kernel_launch(void* const* d_in, const int* in_sizes, int n_in,
                              void* d_out, int out_size, void* d_ws, size_t ws_size,
                              hipStream_t stream) {
  (void)in_sizes; (void)n_in; (void)out_size; (void)ws_size;
  const float* x   = (const float*)d_in[0];
  const float* adj = (const float*)d_in[1];
  const float* wself[3] = {(const float*)d_in[2],  (const float*)d_in[8],  (const float*)d_in[14]};
  const float* bself[3] = {(const float*)d_in[3],  (const float*)d_in[9],  (const float*)d_in[15]};
  const float* wedge[3] = {(const float*)d_in[4],  (const float*)d_in[10], (const float*)d_in[16]};
  const float* bedge[3] = {(const float*)d_in[5],  (const float*)d_in[11], (const float*)d_in[17]};
  const float* bng[3]   = {(const float*)d_in[6],  (const float*)d_in[12], (const float*)d_in[18]};
  const float* bnb[3]   = {(const float*)d_in[7],  (const float*)d_in[13], (const float*)d_in[19]};
  const float* w1   = (const float*)d_in[20];
  const float* b1   = (const float*)d_in[21];
  const float* bnfg = (const float*)d_in[22];
  const float* bnfb = (const float*)d_in[23];
  const float* w2   = (const float*)d_in[24];
  const float* b2   = (const float*)d_in[25];

  char* ws = (char*)d_ws;                 // total 42,078,208 B
  __bf16* mmp = (__bf16*)ws;              // 16,777,216
  float* hA  = (float*)(ws + 16777216);   //  8,388,608
  float* hB  = (float*)(ws + 25165824);   //  8,388,608
  float* hs  = (float*)(ws + 33554432);   //  8,388,608
  float* deg = (float*)(ws + 41943040);   //     65,536
  float* inv = (float*)(ws + 42008576);   //     65,536
  float* ss  = (float*)(ws + 42074112);   //      4,096

  hipMemsetAsync(deg, 0, MBATCH * NNODE * sizeof(float), stream);
  k_deg<<<256, 256, 0, stream>>>(adj, deg);
  k_inv<<<64, 256, 0, stream>>>(deg, inv);

  // layer 0 (K=64, input x)
  k_lin<64, false><<<dim3(256, 2), 256, 0, stream>>>(x, wself[0], bself[0], nullptr, hs, nullptr);
  k_lin<64, true ><<<dim3(256, 8), 256, 0, stream>>>(x, wedge[0], bedge[0], inv, nullptr, mmp);
  k_spmm<<<256, 256, 0, stream>>>(adj, mmp, hs, hA);
  k_stats<<<512, 256, 0, stream>>>(hA, bng[0], bnb[0], ss);
  k_bnrelu<<<2048, 256, 0, stream>>>(hA, ss);

  // layer 1 (K=128, hA -> hB)
  k_lin<128, false><<<dim3(256, 2), 256, 0, stream>>>(hA, wself[1], bself[1], nullptr, hs, nullptr);
  k_lin<128, true ><<<dim3(256, 8), 256, 0, stream>>>(hA, wedge[1], bedge[1], inv, nullptr, mmp);
  k_spmm<<<256, 256, 0, stream>>>(adj, mmp, hs, hB);
  k_stats<<<512, 256, 0, stream>>>(hB, bng[1], bnb[1], ss);
  k_bnrelu<<<2048, 256, 0, stream>>>(hB, ss);

  // layer 2 (K=128, hB -> hA)
  k_lin<128, false><<<dim3(256, 2), 256, 0, stream>>>(hB, wself[2], bself[2], nullptr, hs, nullptr);
  k_lin<128, true ><<<dim3(256, 8), 256, 0, stream>>>(hB, wedge[2], bedge[2], inv, nullptr, mmp);
  k_spmm<<<256, 256, 0, stream>>>(adj, mmp, hs, hA);
  k_stats<<<512, 256, 0, stream>>>(hA, bng[2], bnb[2], ss);
  k_bnrelu<<<2048, 256, 0, stream>>>(hA, ss);

  // head: w1 -> BN -> relu -> w2
  k_lin<128, false><<<dim3(256, 2), 256, 0, stream>>>(hA, w1, b1, nullptr, hs, nullptr);
  k_stats<<<512, 256, 0, stream>>>(hs, bnfg, bnfb, ss);
  k_bnrelu<<<2048, 256, 0, stream>>>(hs, ss);
  k_lin<128, false><<<dim3(256, 2), 256, 0, stream>>>(hs, w2, b2, nullptr, (float*)d_out, nullptr);
}

// Round 2
// 565.591 us; speedup vs baseline: 1.3228x; 1.3228x over previous
//
#include <hip/hip_runtime.h>
#include <stdint.h>

// RGCN round 2: bitmask-compressed adjacency + e-split spmm with atomics.
//
//   k_pack: adj (134 MB, read ONCE) -> bitmask rows (4 MB) + deg (popcount,
//           adj symmetric so row sums == column sums); diag bit zeroed here.
//   per layer:
//     k_lin self  -> layer output buffer (fp32 tiled GEMM)
//     k_lin edge  -> mmp bf16, k-packed [b][e][m>>3][o][m&7], inv folded in
//     k_spmm      -> grid (e slow, b, nt): A = bitmask in regs expanded to
//                    bf16 {0,1} (exact), B = 16KB LDS chunks via
//                    global_load_lds(16B), 16x16x32 bf16 MFMA, atomicAdd out
//     k_stats / k_bnrelu (per-node BN over (b,o), biased var) + relu
//   head: w1 -> BN -> relu -> w2

typedef float  f32x4  __attribute__((ext_vector_type(4)));
typedef __bf16 bf16x8 __attribute__((ext_vector_type(8)));
typedef unsigned short ushort8 __attribute__((ext_vector_type(8)));
typedef uint32_t uint4v __attribute__((ext_vector_type(4)));

#define MBATCH 32
#define ETYPES 4
#define NNODE  512
#define HIDD   128

#define GLB(p) (const __attribute__((address_space(1))) uint32_t*)(p)
#define LDS(p) (__attribute__((address_space(3))) uint32_t*)(p)

// ---------------- pack: adj -> bitmask + deg ----------------
// one wave per (b,e,n) row; 8 ballots of 64 cols each; diag masked; deg += popcount
__global__ __launch_bounds__(256) void k_pack(const float* __restrict__ adj,
                                              uint32_t* __restrict__ bm,
                                              float* __restrict__ deg) {
  int t = threadIdx.x;
  int wave = t >> 6, lane = t & 63;
  int r = blockIdx.x * 4 + wave;          // 65536 rows
  int b = r >> 11, n = r & 511;
  const float* row = adj + (long)r * 512;
  uint32_t myw = 0;
#pragma unroll
  for (int i = 0; i < 8; ++i) {
    uint64_t bal = __ballot(row[i * 64 + lane] != 0.f);
    uint32_t lo = (uint32_t)bal, hi = (uint32_t)(bal >> 32);
    if ((lane >> 1) == i) myw = (lane & 1) ? hi : lo;
  }
  if (lane == (n >> 5)) myw &= ~(1u << (n & 31));   // zero diagonal
  int pc = (lane < 16) ? __popc(myw) : 0;
  pc += __shfl_down(pc, 8);
  pc += __shfl_down(pc, 4);
  pc += __shfl_down(pc, 2);
  pc += __shfl_down(pc, 1);
  if (lane < 16) bm[(long)r * 16 + lane] = myw;
  if (lane == 0) atomicAdd(&deg[b * 512 + n], (float)pc);
}

__global__ __launch_bounds__(256) void k_inv(const float* __restrict__ deg,
                                             float* __restrict__ inv) {
  int i = blockIdx.x * 256 + threadIdx.x;
  float d = deg[i];
  inv[i] = d > 0.f ? 1.f / d : 0.f;
}

// ---------------- fp32 tiled linear (unchanged from r1) ----------------
template <int K, bool EDGE>
__global__ __launch_bounds__(256) void k_lin(const float* __restrict__ h,
                                             const float* __restrict__ W,
                                             const float* __restrict__ bias,
                                             const float* __restrict__ invp,
                                             float* __restrict__ out,
                                             __bf16* __restrict__ mmp) {
  constexpr int WS = EDGE ? 512 : 128;
  __shared__ float wt[K][64];
  __shared__ float ht[64][K];
  int t = threadIdx.x;
  int g0 = blockIdx.x * 64;
  int c0 = blockIdx.y * 64;
  for (int idx = t; idx < K * 16; idx += 256) {
    int k = idx >> 4, c4 = idx & 15;
    *(f32x4*)&wt[k][c4 * 4] = *(const f32x4*)(W + k * WS + c0 + c4 * 4);
  }
  for (int idx = t; idx < 64 * (K / 4); idx += 256) {
    int r = idx / (K / 4), k4 = idx % (K / 4);
    *(f32x4*)&ht[r][k4 * 4] = *(const f32x4*)(h + (g0 + r) * K + k4 * 4);
  }
  __syncthreads();
  int rq = t >> 4, cq = t & 15;
  f32x4 acc[4] = {};
  for (int k0 = 0; k0 < K; k0 += 4) {
    f32x4 hv[4], wv[4];
#pragma unroll
    for (int i = 0; i < 4; ++i) hv[i] = *(const f32x4*)&ht[rq * 4 + i][k0];
#pragma unroll
    for (int j = 0; j < 4; ++j) wv[j] = *(const f32x4*)&wt[k0 + j][cq * 4];
#pragma unroll
    for (int kk = 0; kk < 4; ++kk) {
#pragma unroll
      for (int i = 0; i < 4; ++i) acc[i] += hv[i][kk] * wv[kk];
    }
  }
  f32x4 bias4 = *(const f32x4*)(bias + c0 + cq * 4);
  if (!EDGE) {
#pragma unroll
    for (int i = 0; i < 4; ++i) {
      int g = g0 + rq * 4 + i;
      *(f32x4*)(out + g * HIDD + c0 + cq * 4) = acc[i] + bias4;
    }
  } else {
#pragma unroll
    for (int i = 0; i < 4; ++i) {
      int g = g0 + rq * 4 + i;
      int b = g >> 9, m = g & 511;
      float iv = invp[g];
#pragma unroll
      for (int j = 0; j < 4; ++j) {
        int ce = c0 + cq * 4 + j;
        int o = ce >> 2, e = ce & 3;      // reshape (HID,E)
        float val = (acc[i][j] + bias4[j]) * iv;
        mmp[(((b * ETYPES + e) * 64 + (m >> 3)) * HIDD + o) * 8 + (m & 7)] = (__bf16)val;
      }
    }
  }
}

// ---------------- spmm: out += adjbits(bf16 0/1) @ mmp, e-split, MFMA ----------------
// grid 1024: bid = e*256 + b*8 + nt (e slow -> same-tile atomics de-correlated)
__global__ __launch_bounds__(256) void k_spmm(const uint32_t* __restrict__ bm,
                                              const __bf16* __restrict__ mmp,
                                              float* __restrict__ out) {
  __shared__ __align__(16) __bf16 Bl[8192];   // [oct(8)][o(128)][j(8)]
  int t = threadIdx.x;
  int bid = blockIdx.x;
  int e = bid >> 8, b = (bid >> 3) & 31, nt = bid & 7;
  int n0 = nt * 64;
  int wave = t >> 6, lane = t & 63, l15 = lane & 15, q = lane >> 4;

  // this lane's A-row bitmask (64 B), q-replicated; row = n0 + wave*16 + l15
  const uint32_t* bmrow = bm + ((long)((b * 4 + e) * 512 + n0 + wave * 16 + l15)) * 16;
  uint32_t rm[16];
#pragma unroll
  for (int i = 0; i < 4; ++i) {
    uint4v v = *(const uint4v*)(bmrow + i * 4);
    rm[i * 4 + 0] = v.x; rm[i * 4 + 1] = v.y; rm[i * 4 + 2] = v.z; rm[i * 4 + 3] = v.w;
  }

  const __bf16* Bbase = mmp + (long)(b * 4 + e) * 65536;
  f32x4 acc[8] = {};
#pragma unroll
  for (int mc = 0; mc < 8; ++mc) {
    __syncthreads();   // Bl free from previous iter
    const char* g = (const char*)(Bbase + mc * 8192);
#pragma unroll
    for (int i = 0; i < 4; ++i) {
      __builtin_amdgcn_global_load_lds(GLB(g + i * 4096 + wave * 1024 + lane * 16),
                                       LDS((char*)Bl + i * 4096 + wave * 1024),
                                       16, 0, 0);
    }
    __syncthreads();   // loads drained
#pragma unroll
    for (int kk = 0; kk < 2; ++kk) {
      uint32_t bits = (rm[mc * 2 + kk] >> (q * 8)) & 0xffu;
      ushort8 aus;
#pragma unroll
      for (int j = 0; j < 8; ++j)
        aus[j] = (bits >> j & 1u) ? (unsigned short)0x3F80 : (unsigned short)0;
      union { ushort8 u; bf16x8 v; } cvt; cvt.u = aus;
      bf16x8 af = cvt.v;
#pragma unroll
      for (int c = 0; c < 8; ++c) {
        bf16x8 bfr = *(const bf16x8*)&Bl[(kk * 4 + q) * 1024 + (c * 16 + l15) * 8];
        acc[c] = __builtin_amdgcn_mfma_f32_16x16x32_bf16(af, bfr, acc[c], 0, 0, 0);
      }
    }
  }
#pragma unroll
  for (int c = 0; c < 8; ++c) {
#pragma unroll
    for (int i = 0; i < 4; ++i) {
      int n = n0 + wave * 16 + q * 4 + i;   // D: row=(l>>4)*4+reg, col=l&15
      int o = c * 16 + l15;
      atomicAdd(out + ((long)b * NNODE + n) * HIDD + o, acc[c][i]);
    }
  }
}

// ---------------- BN stats per node n over (b,o) ----------------
__global__ __launch_bounds__(256) void k_stats(const float* __restrict__ hp,
                                               const float* __restrict__ gg,
                                               const float* __restrict__ bb,
                                               float* __restrict__ ss) {
  int n = blockIdx.x, t = threadIdx.x;
  int o4 = t & 31, bq = t >> 5;
  float s = 0.f, sq = 0.f;
#pragma unroll
  for (int i = 0; i < 4; ++i) {
    int b = bq + i * 8;
    f32x4 v = *(const f32x4*)(hp + (b * NNODE + n) * HIDD + o4 * 4);
#pragma unroll
    for (int j = 0; j < 4; ++j) { s += v[j]; sq += v[j] * v[j]; }
  }
  __shared__ float rs[256], rq[256];
  rs[t] = s; rq[t] = sq;
  __syncthreads();
  for (int off = 128; off > 0; off >>= 1) {
    if (t < off) { rs[t] += rs[t + off]; rq[t] += rq[t + off]; }
    __syncthreads();
  }
  if (t == 0) {
    float mean = rs[0] * (1.f / 4096.f);
    float var = rq[0] * (1.f / 4096.f) - mean * mean;
    float rstd = rsqrtf(var + 1e-5f);
    float sc = gg[n] * rstd;
    ss[n] = sc;
    ss[512 + n] = bb[n] - mean * sc;
  }
}

__global__ __launch_bounds__(256) void k_bnrelu(float* __restrict__ h,
                                                const float* __restrict__ ss) {
  int idx = blockIdx.x * 256 + threadIdx.x;
  int n = (idx >> 5) & 511;
  f32x4 v = *(f32x4*)(h + idx * 4);
  float sc = ss[n], sh = ss[512 + n];
#pragma unroll
  for (int j = 0; j < 4; ++j) {
    float x = v[j] * sc + sh;
    v[j] = x > 0.f ? x : 0.f;
  }
  *(f32x4*)(h + idx * 4) = v;
}

extern "C" void kernel_launch(void* const* d_in, const int* in_sizes, int n_in,
                              void* d_out, int out_size, void* d_ws, size_t ws_size,
                              hipStream_t stream) {
  (void)in_sizes; (void)n_in; (void)out_size; (void)ws_size;
  const float* x   = (const float*)d_in[0];
  const float* adj = (const float*)d_in[1];
  const float* wself[3] = {(const float*)d_in[2],  (const float*)d_in[8],  (const float*)d_in[14]};
  const float* bself[3] = {(const float*)d_in[3],  (const float*)d_in[9],  (const float*)d_in[15]};
  const float* wedge[3] = {(const float*)d_in[4],  (const float*)d_in[10], (const float*)d_in[16]};
  const float* bedge[3] = {(const float*)d_in[5],  (const float*)d_in[11], (const float*)d_in[17]};
  const float* bng[3]   = {(const float*)d_in[6],  (const float*)d_in[12], (const float*)d_in[18]};
  const float* bnb[3]   = {(const float*)d_in[7],  (const float*)d_in[13], (const float*)d_in[19]};
  const float* w1   = (const float*)d_in[20];
  const float* b1   = (const float*)d_in[21];
  const float* bnfg = (const float*)d_in[22];
  const float* bnfb = (const float*)d_in[23];
  const float* w2   = (const float*)d_in[24];
  const float* b2   = (const float*)d_in[25];

  char* ws = (char*)d_ws;                        // 37,883,904 B total
  __bf16*   mmp = (__bf16*)ws;                   // 16,777,216
  float*    hA  = (float*)(ws + 16777216);       //  8,388,608
  float*    hB  = (float*)(ws + 25165824);       //  8,388,608
  uint32_t* bm  = (uint32_t*)(ws + 33554432);    //  4,194,304
  float*    deg = (float*)(ws + 37748736);       //     65,536
  float*    inv = (float*)(ws + 37814272);       //     65,536
  float*    ss  = (float*)(ws + 37879808);       //      4,096

  hipMemsetAsync(deg, 0, MBATCH * NNODE * sizeof(float), stream);
  k_pack<<<16384, 256, 0, stream>>>(adj, bm, deg);
  k_inv<<<64, 256, 0, stream>>>(deg, inv);

  // layer 0 (K=64): self -> hA, spmm += into hA
  k_lin<64, false><<<dim3(256, 2), 256, 0, stream>>>(x, wself[0], bself[0], nullptr, hA, nullptr);
  k_lin<64, true ><<<dim3(256, 8), 256, 0, stream>>>(x, wedge[0], bedge[0], inv, nullptr, mmp);
  k_spmm<<<1024, 256, 0, stream>>>(bm, mmp, hA);
  k_stats<<<512, 256, 0, stream>>>(hA, bng[0], bnb[0], ss);
  k_bnrelu<<<2048, 256, 0, stream>>>(hA, ss);

  // layer 1 (K=128): hA -> hB
  k_lin<128, false><<<dim3(256, 2), 256, 0, stream>>>(hA, wself[1], bself[1], nullptr, hB, nullptr);
  k_lin<128, true ><<<dim3(256, 8), 256, 0, stream>>>(hA, wedge[1], bedge[1], inv, nullptr, mmp);
  k_spmm<<<1024, 256, 0, stream>>>(bm, mmp, hB);
  k_stats<<<512, 256, 0, stream>>>(hB, bng[1], bnb[1], ss);
  k_bnrelu<<<2048, 256, 0, stream>>>(hB, ss);

  // layer 2 (K=128): hB -> hA
  k_lin<128, false><<<dim3(256, 2), 256, 0, stream>>>(hB, wself[2], bself[2], nullptr, hA, nullptr);
  k_lin<128, true ><<<dim3(256, 8), 256, 0, stream>>>(hB, wedge[2], bedge[2], inv, nullptr, mmp);
  k_spmm<<<1024, 256, 0, stream>>>(bm, mmp, hA);
  k_stats<<<512, 256, 0, stream>>>(hA, bng[2], bnb[2], ss);
  k_bnrelu<<<2048, 256, 0, stream>>>(hA, ss);

  // head
  k_lin<128, false><<<dim3(256, 2), 256, 0, stream>>>(hA, w1, b1, nullptr, hB, nullptr);
  k_stats<<<512, 256, 0, stream>>>(hB, bnfg, bnfb, ss);
  k_bnrelu<<<2048, 256, 0, stream>>>(hB, ss);
  k_lin<128, false><<<dim3(256, 2), 256, 0, stream>>>(hB, w2, b2, nullptr, (float*)d_out, nullptr);
}

// Round 3
// 485.848 us; speedup vs baseline: 1.5400x; 1.1641x over previous
//
#include <hip/hip_runtime.h>
#include <stdint.h>

// RGCN round 3: all linears -> bf16 MFMA; spmm with 2x row-tile B-frag reuse.
//
//   k_pack: adj (134 MB, read once) -> bitmask (4 MB) + deg (popcount)
//   per layer:
//     k_gemm<K,false>: hpre = h_bf16 @ Wself + bias   (MFMA, fp32 out)
//     k_gemm<K,true> : mmp  = inv * (h @ Wedge + b)   (MFMA, bf16 k-packed out,
//                      e-major column permutation -> fixed e per block,
//                      coalesced bf16x4 scatter)
//     k_spmm: hpre += adjbits @ mmp  (grid 512, 128-row blocks, 2 row-tiles
//             per wave reuse each B-frag ds_read_b128 for 2 MFMAs; atomics)
//     k_stats (fp32) + k_bnrelu16 (fp32 in -> bf16 out)
//   head: gemm w1 -> stats -> bnrelu16 -> gemm w2 -> d_out (fp32)

typedef float  f32x4  __attribute__((ext_vector_type(4)));
typedef __bf16 bf16x8 __attribute__((ext_vector_type(8)));
typedef __bf16 bf16x4 __attribute__((ext_vector_type(4)));
typedef unsigned short ushort8v __attribute__((ext_vector_type(8)));
typedef uint32_t uint4v __attribute__((ext_vector_type(4)));

#define MBATCH 32
#define ETYPES 4
#define NNODE  512
#define HIDD   128

#define GLB(p) (const __attribute__((address_space(1))) uint32_t*)(p)
#define LDSp(p) (__attribute__((address_space(3))) uint32_t*)(p)

// ---------------- pack: adj -> bitmask + deg ----------------
__global__ __launch_bounds__(256) void k_pack(const float* __restrict__ adj,
                                              uint32_t* __restrict__ bm,
                                              float* __restrict__ deg) {
  int t = threadIdx.x;
  int wave = t >> 6, lane = t & 63;
  int r = blockIdx.x * 4 + wave;          // 65536 rows (b,e,n)
  int b = r >> 11, n = r & 511;
  const float* row = adj + (long)r * 512;
  uint32_t myw = 0;
#pragma unroll
  for (int i = 0; i < 8; ++i) {
    uint64_t bal = __ballot(row[i * 64 + lane] != 0.f);
    uint32_t lo = (uint32_t)bal, hi = (uint32_t)(bal >> 32);
    if ((lane >> 1) == i) myw = (lane & 1) ? hi : lo;
  }
  if (lane == (n >> 5)) myw &= ~(1u << (n & 31));   // zero diagonal
  int pc = (lane < 16) ? __popc(myw) : 0;
  pc += __shfl_down(pc, 8);
  pc += __shfl_down(pc, 4);
  pc += __shfl_down(pc, 2);
  pc += __shfl_down(pc, 1);
  if (lane < 16) bm[(long)r * 16 + lane] = myw;
  if (lane == 0) atomicAdd(&deg[b * 512 + n], (float)pc);
}

__global__ __launch_bounds__(256) void k_inv(const float* __restrict__ deg,
                                             float* __restrict__ inv) {
  int i = blockIdx.x * 256 + threadIdx.x;
  float d = deg[i];
  inv[i] = d > 0.f ? 1.f / d : 0.f;
}

__global__ __launch_bounds__(256) void k_cast(const float* __restrict__ in,
                                              __bf16* __restrict__ out) {
  int i = blockIdx.x * 256 + threadIdx.x;
  f32x4 v = *(const f32x4*)(in + (long)i * 4);
  bf16x4 o;
#pragma unroll
  for (int j = 0; j < 4; ++j) o[j] = (__bf16)v[j];
  *(bf16x4*)(out + (long)i * 4) = o;
}

// ---------------- bf16 MFMA linear ----------------
// 64 rows x 64 cols per block, whole K staged (K<=128). 4 waves, wave = 16 rows.
// EDGE: grid.y=8, e = by>>1 fixed per block, o0 = (by&1)*64; W col = o*4+e.
template <int K, bool EDGE>
__global__ __launch_bounds__(256) void k_gemm(const __bf16* __restrict__ h,
                                              const float* __restrict__ W,
                                              const float* __restrict__ bias,
                                              const float* __restrict__ invp,
                                              float* __restrict__ out,
                                              __bf16* __restrict__ mmp) {
  constexpr int WS = EDGE ? 512 : 128;
  __shared__ __bf16 Hl[64][K + 8];
  __shared__ __bf16 Wl[K * 64];           // k-packed [K/8][64][8]
  int t = threadIdx.x;
  int g0 = blockIdx.x * 64;
  int by = blockIdx.y;
  int e  = EDGE ? (by >> 1) : 0;
  int o0 = EDGE ? ((by & 1) * 64) : 0;
  int c0 = EDGE ? 0 : by * 64;
  // stage H (bf16x8, coalesced)
  for (int idx = t; idx < 64 * (K / 8); idx += 256) {
    int r = idx / (K / 8), ch = idx % (K / 8);
    *(bf16x8*)&Hl[r][ch * 8] = *(const bf16x8*)(h + (long)(g0 + r) * K + ch * 8);
  }
  // stage W fp32 -> bf16 k-packed: thread = 4 consecutive k of one col
  for (int idx = t; idx < K * 16; idx += 256) {
    int c = idx & 63, k0 = (idx >> 6) * 4;
    int cg = EDGE ? ((o0 + c) * 4 + e) : (c0 + c);
    bf16x4 v4;
#pragma unroll
    for (int kk = 0; kk < 4; ++kk) v4[kk] = (__bf16)W[(k0 + kk) * WS + cg];
    *(bf16x4*)&Wl[((k0 >> 3) * 64 + c) * 8 + (k0 & 7)] = v4;
  }
  __syncthreads();
  int wave = t >> 6, lane = t & 63, l15 = lane & 15, q = lane >> 4;
  f32x4 acc[4] = {};
#pragma unroll
  for (int kk = 0; kk < K / 32; ++kk) {
    bf16x8 af = *(const bf16x8*)&Hl[wave * 16 + l15][kk * 32 + q * 8];
#pragma unroll
    for (int c = 0; c < 4; ++c) {
      bf16x8 bfr = *(const bf16x8*)&Wl[((kk * 4 + q) * 64 + c * 16 + l15) * 8];
      acc[c] = __builtin_amdgcn_mfma_f32_16x16x32_bf16(af, bfr, acc[c], 0, 0, 0);
    }
  }
  // D: row = q*4+i (in wave's 16-row tile), col = c*16+l15
  if (!EDGE) {
#pragma unroll
    for (int c = 0; c < 4; ++c) {
      float bc = bias[c0 + c * 16 + l15];
#pragma unroll
      for (int i = 0; i < 4; ++i) {
        int g = g0 + wave * 16 + q * 4 + i;
        out[(long)g * HIDD + c0 + c * 16 + l15] = acc[c][i] + bc;
      }
    }
  } else {
    float iv[4];
#pragma unroll
    for (int i = 0; i < 4; ++i) iv[i] = invp[g0 + wave * 16 + q * 4 + i];
    int b4e  = (g0 >> 9) * 4 + e;
    int octg = ((g0 & 511) >> 3) + wave * 2 + (q >> 1);
    int j0   = (q & 1) * 4;
#pragma unroll
    for (int c = 0; c < 4; ++c) {
      int o = o0 + c * 16 + l15;
      float bc = bias[o * 4 + e];
      bf16x4 v4;
#pragma unroll
      for (int i = 0; i < 4; ++i) v4[i] = (__bf16)((acc[c][i] + bc) * iv[i]);
      *(bf16x4*)(mmp + ((long)(b4e * 64 + octg) * HIDD + o) * 8 + j0) = v4;
    }
  }
}

// ---------------- spmm: out += adjbits(bf16 0/1) @ mmp ----------------
// grid 512: bid = e*128 + b*4 + nt. Block = 128 rows; wave = 2 x 16-row tiles
// sharing each B-frag read (ds_read_b128 feeds 2 MFMAs).
__global__ __launch_bounds__(256) void k_spmm(const uint32_t* __restrict__ bm,
                                              const __bf16* __restrict__ mmp,
                                              float* __restrict__ out) {
  __shared__ __align__(16) __bf16 Bl[8192];   // [oct(8)][o(128)][j(8)]
  int t = threadIdx.x;
  int bid = blockIdx.x;
  int e = bid >> 7, b = (bid >> 2) & 31, nt = bid & 3;
  int n0 = nt * 128;
  int wave = t >> 6, lane = t & 63, l15 = lane & 15, q = lane >> 4;

  // bitmask rows: tile0 = n0 + wave*32 + l15, tile1 = +16
  const uint32_t* bmr0 = bm + ((long)((b * 4 + e) * 512 + n0 + wave * 32 + l15)) * 16;
  uint32_t rm0[16], rm1[16];
#pragma unroll
  for (int i = 0; i < 4; ++i) {
    uint4v v0 = *(const uint4v*)(bmr0 + i * 4);
    uint4v v1 = *(const uint4v*)(bmr0 + 256 + i * 4);   // +16 rows * 16 words
    rm0[i * 4 + 0] = v0.x; rm0[i * 4 + 1] = v0.y; rm0[i * 4 + 2] = v0.z; rm0[i * 4 + 3] = v0.w;
    rm1[i * 4 + 0] = v1.x; rm1[i * 4 + 1] = v1.y; rm1[i * 4 + 2] = v1.z; rm1[i * 4 + 3] = v1.w;
  }

  const __bf16* Bbase = mmp + (long)(b * 4 + e) * 65536;
  f32x4 acc0[8] = {}, acc1[8] = {};
#pragma unroll 1
  for (int mc = 0; mc < 8; ++mc) {
    __syncthreads();
    const char* g = (const char*)(Bbase + mc * 8192);
#pragma unroll
    for (int i = 0; i < 4; ++i) {
      __builtin_amdgcn_global_load_lds(GLB(g + i * 4096 + wave * 1024 + lane * 16),
                                       LDSp((char*)Bl + i * 4096 + wave * 1024),
                                       16, 0, 0);
    }
    __syncthreads();
#pragma unroll
    for (int kk = 0; kk < 2; ++kk) {
      uint32_t bits0 = (rm0[mc * 2 + kk] >> (q * 8)) & 0xffu;
      uint32_t bits1 = (rm1[mc * 2 + kk] >> (q * 8)) & 0xffu;
      ushort8v a0, a1;
#pragma unroll
      for (int j = 0; j < 8; ++j) {
        a0[j] = (bits0 >> j & 1u) ? (unsigned short)0x3F80 : (unsigned short)0;
        a1[j] = (bits1 >> j & 1u) ? (unsigned short)0x3F80 : (unsigned short)0;
      }
      union { ushort8v u; bf16x8 v; } c0, c1; c0.u = a0; c1.u = a1;
#pragma unroll
      for (int c = 0; c < 8; ++c) {
        bf16x8 bfr = *(const bf16x8*)&Bl[(kk * 4 + q) * 1024 + (c * 16 + l15) * 8];
        acc0[c] = __builtin_amdgcn_mfma_f32_16x16x32_bf16(c0.v, bfr, acc0[c], 0, 0, 0);
        acc1[c] = __builtin_amdgcn_mfma_f32_16x16x32_bf16(c1.v, bfr, acc1[c], 0, 0, 0);
      }
    }
  }
#pragma unroll
  for (int c = 0; c < 8; ++c) {
#pragma unroll
    for (int i = 0; i < 4; ++i) {
      int n = n0 + wave * 32 + q * 4 + i;
      int o = c * 16 + l15;
      atomicAdd(out + ((long)b * NNODE + n) * HIDD + o, acc0[c][i]);
      atomicAdd(out + ((long)b * NNODE + n + 16) * HIDD + o, acc1[c][i]);
    }
  }
}

// ---------------- BN stats per node n over (b,o) ----------------
__global__ __launch_bounds__(256) void k_stats(const float* __restrict__ hp,
                                               const float* __restrict__ gg,
                                               const float* __restrict__ bb,
                                               float* __restrict__ ss) {
  int n = blockIdx.x, t = threadIdx.x;
  int o4 = t & 31, bq = t >> 5;
  float s = 0.f, sq = 0.f;
#pragma unroll
  for (int i = 0; i < 4; ++i) {
    int b = bq + i * 8;
    f32x4 v = *(const f32x4*)(hp + ((long)b * NNODE + n) * HIDD + o4 * 4);
#pragma unroll
    for (int j = 0; j < 4; ++j) { s += v[j]; sq += v[j] * v[j]; }
  }
  __shared__ float rs[256], rq[256];
  rs[t] = s; rq[t] = sq;
  __syncthreads();
  for (int off = 128; off > 0; off >>= 1) {
    if (t < off) { rs[t] += rs[t + off]; rq[t] += rq[t + off]; }
    __syncthreads();
  }
  if (t == 0) {
    float mean = rs[0] * (1.f / 4096.f);
    float var = rq[0] * (1.f / 4096.f) - mean * mean;
    float rstd = rsqrtf(var + 1e-5f);
    float sc = gg[n] * rstd;
    ss[n] = sc;
    ss[512 + n] = bb[n] - mean * sc;
  }
}

// fp32 in -> bf16 out (next layer consumes bf16)
__global__ __launch_bounds__(256) void k_bnrelu16(const float* __restrict__ hp,
                                                  const float* __restrict__ ss,
                                                  __bf16* __restrict__ hb) {
  int idx = blockIdx.x * 256 + threadIdx.x;   // f32x4 index, grid 2048
  int n = (idx >> 5) & 511;
  f32x4 v = *(const f32x4*)(hp + (long)idx * 4);
  float sc = ss[n], sh = ss[512 + n];
  bf16x4 o;
#pragma unroll
  for (int j = 0; j < 4; ++j) {
    float x = v[j] * sc + sh;
    o[j] = (__bf16)(x > 0.f ? x : 0.f);
  }
  *(bf16x4*)(hb + (long)idx * 4) = o;
}

extern "C" void kernel_launch(void* const* d_in, const int* in_sizes, int n_in,
                              void* d_out, int out_size, void* d_ws, size_t ws_size,
                              hipStream_t stream) {
  (void)in_sizes; (void)n_in; (void)out_size; (void)ws_size;
  const float* x   = (const float*)d_in[0];
  const float* adj = (const float*)d_in[1];
  const float* wself[3] = {(const float*)d_in[2],  (const float*)d_in[8],  (const float*)d_in[14]};
  const float* bself[3] = {(const float*)d_in[3],  (const float*)d_in[9],  (const float*)d_in[15]};
  const float* wedge[3] = {(const float*)d_in[4],  (const float*)d_in[10], (const float*)d_in[16]};
  const float* bedge[3] = {(const float*)d_in[5],  (const float*)d_in[11], (const float*)d_in[17]};
  const float* bng[3]   = {(const float*)d_in[6],  (const float*)d_in[12], (const float*)d_in[18]};
  const float* bnb[3]   = {(const float*)d_in[7],  (const float*)d_in[13], (const float*)d_in[19]};
  const float* w1   = (const float*)d_in[20];
  const float* b1   = (const float*)d_in[21];
  const float* bnfg = (const float*)d_in[22];
  const float* bnfb = (const float*)d_in[23];
  const float* w2   = (const float*)d_in[24];
  const float* b2   = (const float*)d_in[25];

  char* ws = (char*)d_ws;                        // 39,981,056 B total
  __bf16*   mmp  = (__bf16*)ws;                  // 16,777,216
  float*    hpre = (float*)(ws + 16777216);      //  8,388,608
  __bf16*   hb0  = (__bf16*)(ws + 25165824);     //  4,194,304
  __bf16*   hb1  = (__bf16*)(ws + 29360128);     //  4,194,304
  __bf16*   xb   = (__bf16*)(ws + 33554432);     //  2,097,152
  uint32_t* bm   = (uint32_t*)(ws + 35651584);   //  4,194,304
  float*    deg  = (float*)(ws + 39845888);      //     65,536
  float*    inv  = (float*)(ws + 39911424);      //     65,536
  float*    ss   = (float*)(ws + 39976960);      //      4,096

  hipMemsetAsync(deg, 0, MBATCH * NNODE * sizeof(float), stream);
  k_cast<<<1024, 256, 0, stream>>>(x, xb);
  k_pack<<<16384, 256, 0, stream>>>(adj, bm, deg);
  k_inv<<<64, 256, 0, stream>>>(deg, inv);

  // layer 0 (K=64)
  k_gemm<64, false><<<dim3(256, 2), 256, 0, stream>>>(xb, wself[0], bself[0], nullptr, hpre, nullptr);
  k_gemm<64, true ><<<dim3(256, 8), 256, 0, stream>>>(xb, wedge[0], bedge[0], inv, nullptr, mmp);
  k_spmm<<<512, 256, 0, stream>>>(bm, mmp, hpre);
  k_stats<<<512, 256, 0, stream>>>(hpre, bng[0], bnb[0], ss);
  k_bnrelu16<<<2048, 256, 0, stream>>>(hpre, ss, hb0);

  // layer 1 (K=128)
  k_gemm<128, false><<<dim3(256, 2), 256, 0, stream>>>(hb0, wself[1], bself[1], nullptr, hpre, nullptr);
  k_gemm<128, true ><<<dim3(256, 8), 256, 0, stream>>>(hb0, wedge[1], bedge[1], inv, nullptr, mmp);
  k_spmm<<<512, 256, 0, stream>>>(bm, mmp, hpre);
  k_stats<<<512, 256, 0, stream>>>(hpre, bng[1], bnb[1], ss);
  k_bnrelu16<<<2048, 256, 0, stream>>>(hpre, ss, hb1);

  // layer 2 (K=128)
  k_gemm<128, false><<<dim3(256, 2), 256, 0, stream>>>(hb1, wself[2], bself[2], nullptr, hpre, nullptr);
  k_gemm<128, true ><<<dim3(256, 8), 256, 0, stream>>>(hb1, wedge[2], bedge[2], inv, nullptr, mmp);
  k_spmm<<<512, 256, 0, stream>>>(bm, mmp, hpre);
  k_stats<<<512, 256, 0, stream>>>(hpre, bng[2], bnb[2], ss);
  k_bnrelu16<<<2048, 256, 0, stream>>>(hpre, ss, hb0);

  // head
  k_gemm<128, false><<<dim3(256, 2), 256, 0, stream>>>(hb0, w1, b1, nullptr, hpre, nullptr);
  k_stats<<<512, 256, 0, stream>>>(hpre, bnfg, bnfb, ss);
  k_bnrelu16<<<2048, 256, 0, stream>>>(hpre, ss, hb1);
  k_gemm<128, false><<<dim3(256, 2), 256, 0, stream>>>(hb1, w2, b2, nullptr, (float*)d_out, nullptr);
}

// Round 4
// 372.722 us; speedup vs baseline: 2.0074x; 1.3035x over previous
//
#include <hip/hip_runtime.h>
#include <stdint.h>

// RGCN round 4: pre-packed bf16 weights (k_prep), fused self+edge GEMM,
// atomic-free spmm (per-e partial buffers), fused BN-stats+BN+ReLU.
//
//   k_pack: adj (134 MB, read once) -> bitmask (4 MB) + deg (popcount)
//   k_prep: all 8 weight mats -> k-packed bf16 blocks (64-col MFMA layout)
//   per layer:
//     k_gemm<K>: grid(256,10): by<2 self cols -> hs (f32); by>=2 edge block
//                (fixed e, 64 o's) -> mmp bf16 k-packed, inv folded.
//                H: padded-LDS bf16x8 staging; W: contiguous global_load_lds.
//     k_spmm:   grid 512 (e,b,nt): adjbits -> bf16 {0,1} A-frags in regs,
//               B chunks via global_load_lds(16B); plain stores to part[e].
//     k_bnstat<true>: block per node n: v = hs + sum_e part[e] (LDS-resident),
//               BN stats over (b,o), normalize+ReLU, write bf16.
//   head: gemm w1 -> k_bnstat<false> -> gemm w2 -> d_out (f32)

typedef float  f32x4  __attribute__((ext_vector_type(4)));
typedef __bf16 bf16x8 __attribute__((ext_vector_type(8)));
typedef __bf16 bf16x4 __attribute__((ext_vector_type(4)));
typedef unsigned short ushort8v __attribute__((ext_vector_type(8)));
typedef uint32_t uint4v __attribute__((ext_vector_type(4)));

#define MBATCH 32
#define ETYPES 4
#define NNODE  512
#define HIDD   128

#define GLB(p) (const __attribute__((address_space(1))) uint32_t*)(p)
#define LDSp(p) (__attribute__((address_space(3))) uint32_t*)(p)

// packed-weight pool offsets (elements)
#define WP_S0 0
#define WP_E0 8192
#define WP_S1 40960
#define WP_E1 57344
#define WP_S2 122880
#define WP_E2 139264
#define WP_W1 204800
#define WP_W2 221184
#define WP_TOT 237568

// ---------------- pack: adj -> bitmask + deg ----------------
__global__ __launch_bounds__(256) void k_pack(const float* __restrict__ adj,
                                              uint32_t* __restrict__ bm,
                                              float* __restrict__ deg) {
  int t = threadIdx.x;
  int wave = t >> 6, lane = t & 63;
  int r = blockIdx.x * 4 + wave;          // 65536 rows (b,e,n)
  int b = r >> 11, n = r & 511;
  const float* row = adj + (long)r * 512;
  uint32_t myw = 0;
#pragma unroll
  for (int i = 0; i < 8; ++i) {
    uint64_t bal = __ballot(row[i * 64 + lane] != 0.f);
    uint32_t lo = (uint32_t)bal, hi = (uint32_t)(bal >> 32);
    if ((lane >> 1) == i) myw = (lane & 1) ? hi : lo;
  }
  if (lane == (n >> 5)) myw &= ~(1u << (n & 31));   // zero diagonal
  int pc = (lane < 16) ? __popc(myw) : 0;
  pc += __shfl_down(pc, 8);
  pc += __shfl_down(pc, 4);
  pc += __shfl_down(pc, 2);
  pc += __shfl_down(pc, 1);
  if (lane < 16) bm[(long)r * 16 + lane] = myw;
  if (lane == 0) atomicAdd(&deg[b * 512 + n], (float)pc);
}

__global__ __launch_bounds__(256) void k_inv(const float* __restrict__ deg,
                                             float* __restrict__ inv) {
  int i = blockIdx.x * 256 + threadIdx.x;
  float d = deg[i];
  inv[i] = d > 0.f ? 1.f / d : 0.f;
}

__global__ __launch_bounds__(256) void k_cast(const float* __restrict__ in,
                                              __bf16* __restrict__ out) {
  int i = blockIdx.x * 256 + threadIdx.x;
  f32x4 v = *(const f32x4*)(in + (long)i * 4);
  bf16x4 o;
#pragma unroll
  for (int j = 0; j < 4; ++j) o[j] = (__bf16)v[j];
  *(bf16x4*)(out + (long)i * 4) = o;
}

// ---------------- prep: pack weights to bf16 k-packed 64-col blocks ----------------
// dst block layout: [blk][k>>3][c(64)][k&7]; self: src col = blk*64+c;
// edge: e = blk>>1, o0 = (blk&1)*64, src col = (o0+c)*4+e (W stride 512).
__global__ __launch_bounds__(256) void k_prep(const float* ws0, const float* we0,
                                              const float* ws1, const float* we1,
                                              const float* ws2, const float* we2,
                                              const float* w1,  const float* w2,
                                              __bf16* __restrict__ dst) {
  int wid = blockIdx.y;
  const float* W; int K, nblk, edge, off;
  switch (wid) {
    case 0:  W = ws0; K = 64;  nblk = 2; edge = 0; off = WP_S0; break;
    case 1:  W = we0; K = 64;  nblk = 8; edge = 1; off = WP_E0; break;
    case 2:  W = ws1; K = 128; nblk = 2; edge = 0; off = WP_S1; break;
    case 3:  W = we1; K = 128; nblk = 8; edge = 1; off = WP_E1; break;
    case 4:  W = ws2; K = 128; nblk = 2; edge = 0; off = WP_S2; break;
    case 5:  W = we2; K = 128; nblk = 8; edge = 1; off = WP_E2; break;
    case 6:  W = w1;  K = 128; nblk = 2; edge = 0; off = WP_W1; break;
    default: W = w2;  K = 128; nblk = 2; edge = 0; off = WP_W2; break;
  }
  int idx = blockIdx.x * 256 + threadIdx.x;
  if (idx >= K * nblk * 64) return;
  int c = idx & 63;
  int k = (idx >> 6) % K;
  int blk = (idx >> 6) / K;
  int WS = edge ? 512 : 128;
  int col = edge ? (((blk & 1) * 64 + c) * 4 + (blk >> 1)) : (blk * 64 + c);
  dst[off + (long)blk * K * 64 + (k >> 3) * 512 + c * 8 + (k & 7)] = (__bf16)W[k * WS + col];
}

// ---------------- fused self+edge bf16 MFMA linear ----------------
// grid (256, NY). by<2: self cols c0=by*64 -> outF (f32, +bias).
// by>=2: edge block blk=by-2 (fixed e, 64 o's) -> mmp bf16 k-packed, *inv.
template <int K>
__global__ __launch_bounds__(256) void k_gemm(const __bf16* __restrict__ h,
                                              const __bf16* __restrict__ wp_self,
                                              const float* __restrict__ bias_self,
                                              const __bf16* __restrict__ wp_edge,
                                              const float* __restrict__ bias_edge,
                                              const float* __restrict__ invp,
                                              float* __restrict__ outF,
                                              __bf16* __restrict__ mmp) {
  __shared__ __bf16 Hl[64][K + 8];
  __shared__ __align__(16) __bf16 Wl[K * 64];   // k-packed [K/8][64][8]
  int t = threadIdx.x;
  int g0 = blockIdx.x * 64;
  int by = blockIdx.y;
  bool edge = by >= 2;
  int wave = t >> 6, lane = t & 63;
  // stage W: contiguous K*128-byte copy via global_load_lds
  {
    const __bf16* wblk = edge ? (wp_edge + (long)(by - 2) * K * 64)
                              : (wp_self + (long)by * K * 64);
    const char* g = (const char*)wblk;
#pragma unroll
    for (int i = 0; i < K / 32; ++i) {
      __builtin_amdgcn_global_load_lds(GLB(g + i * 4096 + wave * 1024 + lane * 16),
                                       LDSp((char*)Wl + i * 4096 + wave * 1024),
                                       16, 0, 0);
    }
  }
  // stage H (bf16x8, coalesced, padded rows)
  for (int idx = t; idx < 64 * (K / 8); idx += 256) {
    int r = idx / (K / 8), ch = idx % (K / 8);
    *(bf16x8*)&Hl[r][ch * 8] = *(const bf16x8*)(h + (long)(g0 + r) * K + ch * 8);
  }
  __syncthreads();
  int l15 = lane & 15, q = lane >> 4;
  f32x4 acc[4] = {};
#pragma unroll
  for (int kk = 0; kk < K / 32; ++kk) {
    bf16x8 af = *(const bf16x8*)&Hl[wave * 16 + l15][kk * 32 + q * 8];
#pragma unroll
    for (int c = 0; c < 4; ++c) {
      bf16x8 bfr = *(const bf16x8*)&Wl[((kk * 4 + q) * 64 + c * 16 + l15) * 8];
      acc[c] = __builtin_amdgcn_mfma_f32_16x16x32_bf16(af, bfr, acc[c], 0, 0, 0);
    }
  }
  // D: row = q*4+i (within wave's 16-row tile), col = c*16+l15
  if (!edge) {
    int c0 = by * 64;
#pragma unroll
    for (int c = 0; c < 4; ++c) {
      float bc = bias_self[c0 + c * 16 + l15];
#pragma unroll
      for (int i = 0; i < 4; ++i) {
        int g = g0 + wave * 16 + q * 4 + i;
        outF[(long)g * HIDD + c0 + c * 16 + l15] = acc[c][i] + bc;
      }
    }
  } else {
    int blk = by - 2;
    int e = blk >> 1, o0 = (blk & 1) * 64;
    float iv[4];
#pragma unroll
    for (int i = 0; i < 4; ++i) iv[i] = invp[g0 + wave * 16 + q * 4 + i];
    int b4e  = (g0 >> 9) * 4 + e;
    int octg = ((g0 & 511) >> 3) + wave * 2 + (q >> 1);
    int j0   = (q & 1) * 4;
#pragma unroll
    for (int c = 0; c < 4; ++c) {
      int o = o0 + c * 16 + l15;
      float bc = bias_edge[o * 4 + e];
      bf16x4 v4;
#pragma unroll
      for (int i = 0; i < 4; ++i) v4[i] = (__bf16)((acc[c][i] + bc) * iv[i]);
      *(bf16x4*)(mmp + ((long)(b4e * 64 + octg) * HIDD + o) * 8 + j0) = v4;
    }
  }
}

// ---------------- spmm: part[e] = adjbits(bf16 0/1) @ mmp ----------------
// grid 512: bid = e*128 + b*4 + nt. Block 128 rows; wave = 2 x 16-row tiles
// sharing each B-frag ds_read_b128. Plain stores (no atomics).
__global__ __launch_bounds__(256) void k_spmm(const uint32_t* __restrict__ bm,
                                              const __bf16* __restrict__ mmp,
                                              float* __restrict__ part) {
  __shared__ __align__(16) __bf16 Bl[8192];   // [oct(8)][o(128)][j(8)]
  int t = threadIdx.x;
  int bid = blockIdx.x;
  int e = bid >> 7, b = (bid >> 2) & 31, nt = bid & 3;
  int n0 = nt * 128;
  int wave = t >> 6, lane = t & 63, l15 = lane & 15, q = lane >> 4;

  const uint32_t* bmr0 = bm + ((long)((b * 4 + e) * 512 + n0 + wave * 32 + l15)) * 16;
  uint32_t rm0[16], rm1[16];
#pragma unroll
  for (int i = 0; i < 4; ++i) {
    uint4v v0 = *(const uint4v*)(bmr0 + i * 4);
    uint4v v1 = *(const uint4v*)(bmr0 + 256 + i * 4);   // +16 rows * 16 words
    rm0[i * 4 + 0] = v0.x; rm0[i * 4 + 1] = v0.y; rm0[i * 4 + 2] = v0.z; rm0[i * 4 + 3] = v0.w;
    rm1[i * 4 + 0] = v1.x; rm1[i * 4 + 1] = v1.y; rm1[i * 4 + 2] = v1.z; rm1[i * 4 + 3] = v1.w;
  }

  const __bf16* Bbase = mmp + (long)(b * 4 + e) * 65536;
  f32x4 acc0[8] = {}, acc1[8] = {};
#pragma unroll 1
  for (int mc = 0; mc < 8; ++mc) {
    __syncthreads();
    const char* g = (const char*)(Bbase + mc * 8192);
#pragma unroll
    for (int i = 0; i < 4; ++i) {
      __builtin_amdgcn_global_load_lds(GLB(g + i * 4096 + wave * 1024 + lane * 16),
                                       LDSp((char*)Bl + i * 4096 + wave * 1024),
                                       16, 0, 0);
    }
    __syncthreads();
#pragma unroll
    for (int kk = 0; kk < 2; ++kk) {
      uint32_t bits0 = (rm0[mc * 2 + kk] >> (q * 8)) & 0xffu;
      uint32_t bits1 = (rm1[mc * 2 + kk] >> (q * 8)) & 0xffu;
      ushort8v a0, a1;
#pragma unroll
      for (int j = 0; j < 8; ++j) {
        a0[j] = (bits0 >> j & 1u) ? (unsigned short)0x3F80 : (unsigned short)0;
        a1[j] = (bits1 >> j & 1u) ? (unsigned short)0x3F80 : (unsigned short)0;
      }
      union { ushort8v u; bf16x8 v; } c0, c1; c0.u = a0; c1.u = a1;
#pragma unroll
      for (int c = 0; c < 8; ++c) {
        bf16x8 bfr = *(const bf16x8*)&Bl[(kk * 4 + q) * 1024 + (c * 16 + l15) * 8];
        acc0[c] = __builtin_amdgcn_mfma_f32_16x16x32_bf16(c0.v, bfr, acc0[c], 0, 0, 0);
        acc1[c] = __builtin_amdgcn_mfma_f32_16x16x32_bf16(c1.v, bfr, acc1[c], 0, 0, 0);
      }
    }
  }
  float* dst = part + (long)(e * 32 + b) * NNODE * HIDD;
#pragma unroll
  for (int c = 0; c < 8; ++c) {
#pragma unroll
    for (int i = 0; i < 4; ++i) {
      int n = n0 + wave * 32 + q * 4 + i;
      int o = c * 16 + l15;
      dst[(long)n * HIDD + o] = acc0[c][i];
      dst[(long)(n + 16) * HIDD + o] = acc1[c][i];
    }
  }
}

// ---------------- fused BN: v = hs (+ sum_e part), stats over (b,o), norm+relu -> bf16 ----------------
template <bool HASP>
__global__ __launch_bounds__(256) void k_bnstat(const float* __restrict__ hs,
                                                const float* __restrict__ part,
                                                const float* __restrict__ gg,
                                                const float* __restrict__ bb,
                                                __bf16* __restrict__ hb) {
  int n = blockIdx.x, t = threadIdx.x;
  int o4 = t & 31, bq = t >> 5;
  __shared__ float sm[4096];
  __shared__ float rs[256], rq[256];
  __shared__ float bc[2];
  float s = 0.f, sq = 0.f;
#pragma unroll
  for (int i = 0; i < 4; ++i) {
    int b = bq + i * 8;
    long base = ((long)b * NNODE + n) * HIDD + o4 * 4;
    f32x4 v = *(const f32x4*)(hs + base);
    if (HASP) {
#pragma unroll
      for (int e = 0; e < 4; ++e)
        v += *(const f32x4*)(part + ((long)(e * 32 + b) * NNODE + n) * HIDD + o4 * 4);
    }
    *(f32x4*)&sm[b * 128 + o4 * 4] = v;
#pragma unroll
    for (int j = 0; j < 4; ++j) { s += v[j]; sq += v[j] * v[j]; }
  }
  rs[t] = s; rq[t] = sq;
  __syncthreads();
  for (int off = 128; off > 0; off >>= 1) {
    if (t < off) { rs[t] += rs[t + off]; rq[t] += rq[t + off]; }
    __syncthreads();
  }
  if (t == 0) {
    float mean = rs[0] * (1.f / 4096.f);
    float var = rq[0] * (1.f / 4096.f) - mean * mean;
    float rstd = rsqrtf(var + 1e-5f);
    float sc = gg[n] * rstd;
    bc[0] = sc;
    bc[1] = bb[n] - mean * sc;
  }
  __syncthreads();
  float sc = bc[0], sh = bc[1];
#pragma unroll
  for (int i = 0; i < 4; ++i) {
    int b = bq + i * 8;
    f32x4 v = *(const f32x4*)&sm[b * 128 + o4 * 4];
    bf16x4 o;
#pragma unroll
    for (int j = 0; j < 4; ++j) {
      float x = v[j] * sc + sh;
      o[j] = (__bf16)(x > 0.f ? x : 0.f);
    }
    *(bf16x4*)(hb + ((long)b * NNODE + n) * HIDD + o4 * 4) = o;
  }
}

extern "C" void kernel_launch(void* const* d_in, const int* in_sizes, int n_in,
                              void* d_out, int out_size, void* d_ws, size_t ws_size,
                              hipStream_t stream) {
  (void)in_sizes; (void)n_in; (void)out_size; (void)ws_size;
  const float* x   = (const float*)d_in[0];
  const float* adj = (const float*)d_in[1];
  const float* wself[3] = {(const float*)d_in[2],  (const float*)d_in[8],  (const float*)d_in[14]};
  const float* bself[3] = {(const float*)d_in[3],  (const float*)d_in[9],  (const float*)d_in[15]};
  const float* wedge[3] = {(const float*)d_in[4],  (const float*)d_in[10], (const float*)d_in[16]};
  const float* bedge[3] = {(const float*)d_in[5],  (const float*)d_in[11], (const float*)d_in[17]};
  const float* bng[3]   = {(const float*)d_in[6],  (const float*)d_in[12], (const float*)d_in[18]};
  const float* bnb[3]   = {(const float*)d_in[7],  (const float*)d_in[13], (const float*)d_in[19]};
  const float* w1   = (const float*)d_in[20];
  const float* b1   = (const float*)d_in[21];
  const float* bnfg = (const float*)d_in[22];
  const float* bnfb = (const float*)d_in[23];
  const float* w2   = (const float*)d_in[24];
  const float* b2   = (const float*)d_in[25];

  char* ws = (char*)d_ws;
  __bf16*   mmp  = (__bf16*)ws;                  // 16,777,216
  float*    hs   = (float*)(ws + 16777216);      //  8,388,608
  float*    part = (float*)(ws + 25165824);      // 33,554,432 (4 x 8 MB)
  __bf16*   hb0  = (__bf16*)(ws + 58720256);     //  4,194,304
  __bf16*   hb1  = (__bf16*)(ws + 62914560);     //  4,194,304
  __bf16*   xb   = (__bf16*)(ws + 67108864);     //  2,097,152
  uint32_t* bm   = (uint32_t*)(ws + 69206016);   //  4,194,304
  float*    deg  = (float*)(ws + 73400320);      //     65,536
  float*    inv  = (float*)(ws + 73465856);      //     65,536
  __bf16*   wp   = (__bf16*)(ws + 73531392);     //    475,136  -> 74,006,528 total

  hipMemsetAsync(deg, 0, MBATCH * NNODE * sizeof(float), stream);
  k_cast<<<1024, 256, 0, stream>>>(x, xb);
  k_pack<<<16384, 256, 0, stream>>>(adj, bm, deg);
  k_inv<<<64, 256, 0, stream>>>(deg, inv);
  k_prep<<<dim3(256, 8), 256, 0, stream>>>(wself[0], wedge[0], wself[1], wedge[1],
                                           wself[2], wedge[2], w1, w2, wp);

  // layer 0 (K=64)
  k_gemm<64><<<dim3(256, 10), 256, 0, stream>>>(xb, wp + WP_S0, bself[0], wp + WP_E0,
                                                bedge[0], inv, hs, mmp);
  k_spmm<<<512, 256, 0, stream>>>(bm, mmp, part);
  k_bnstat<true><<<512, 256, 0, stream>>>(hs, part, bng[0], bnb[0], hb0);

  // layer 1 (K=128)
  k_gemm<128><<<dim3(256, 10), 256, 0, stream>>>(hb0, wp + WP_S1, bself[1], wp + WP_E1,
                                                 bedge[1], inv, hs, mmp);
  k_spmm<<<512, 256, 0, stream>>>(bm, mmp, part);
  k_bnstat<true><<<512, 256, 0, stream>>>(hs, part, bng[1], bnb[1], hb1);

  // layer 2 (K=128)
  k_gemm<128><<<dim3(256, 10), 256, 0, stream>>>(hb1, wp + WP_S2, bself[2], wp + WP_E2,
                                                 bedge[2], inv, hs, mmp);
  k_spmm<<<512, 256, 0, stream>>>(bm, mmp, part);
  k_bnstat<true><<<512, 256, 0, stream>>>(hs, part, bng[2], bnb[2], hb0);

  // head
  k_gemm<128><<<dim3(256, 2), 256, 0, stream>>>(hb0, wp + WP_W1, b1, nullptr,
                                                nullptr, nullptr, hs, nullptr);
  k_bnstat<false><<<512, 256, 0, stream>>>(hs, nullptr, bnfg, bnfb, hb1);
  k_gemm<128><<<dim3(256, 2), 256, 0, stream>>>(hb1, wp + WP_W2, b2, nullptr,
                                                nullptr, nullptr, (float*)d_out, nullptr);
}